// Round 12
// baseline (717.850 us; speedup 1.0000x reference)
//
#include <hip/hip_runtime.h>

#define N_NODES  50000
#define N_EDGES  800000
#define D_IN     64
#define D_RADIAL 128
#define NTILES   (N_EDGES / 64)   // 12500, exact

typedef __bf16 bf16x8 __attribute__((ext_vector_type(8)));
typedef float  f32x4  __attribute__((ext_vector_type(4)));
typedef short  s16x8  __attribute__((ext_vector_type(8)));

// pack two f32 -> two bf16 (truncation) in one v_perm (MFMA inputs)
__device__ inline unsigned int pack_bf16_pair(float lo, float hi) {
    return __builtin_amdgcn_perm(__float_as_uint(hi), __float_as_uint(lo), 0x07060302u);
}

// round-to-nearest-even f32 -> bf16
__device__ inline unsigned short f2bf_rne(float f) {
    unsigned int u = __float_as_uint(f);
    u += 0x7FFFu + ((u >> 16) & 1u);
    return (unsigned short)(u >> 16);
}

// ---------------- workspace layout (CSR path) ----------------
constexpr size_t ws_align(size_t x) { return (x + 255) & ~(size_t)255; }
constexpr size_t WS_CNT  = 0;                                             // int[N_NODES]
constexpr size_t WS_OFF  = ws_align(WS_CNT  + (size_t)N_NODES * 4);       // int[N_NODES+1]
constexpr size_t WS_CUR  = ws_align(WS_OFF  + (size_t)(N_NODES + 1) * 4); // int[N_NODES]
constexpr size_t WS_BSUM = ws_align(WS_CUR  + (size_t)N_NODES * 4);       // int[128]
constexpr size_t WS_EORD = ws_align(WS_BSUM + 512);                       // int[N_EDGES] eord[pos] = edge id
constexpr size_t WS_SSRC = ws_align(WS_EORD + (size_t)N_EDGES * 4);       // int[N_EDGES] ssrc[pos] = src[eord[pos]]
constexpr size_t WS_SDST = ws_align(WS_SSRC + (size_t)N_EDGES * 4);       // int[N_EDGES] sdst[pos] = dst[eord[pos]] (nondecreasing)
constexpr size_t WS_REQUIRED = WS_SDST + (size_t)N_EDGES * 4;             // ~16 MB

#define SCAN_B    512
#define SCAN_NBLK ((N_NODES + SCAN_B - 1) / SCAN_B)   // 98
static_assert(SCAN_NBLK <= 128, "scan_tops assumes <=128 blocks");

// ---------------- sort kernels ----------------
__global__ __launch_bounds__(256) void hist_kernel(const int* __restrict__ dst,
                                                   int* __restrict__ cnt) {
    int i = blockIdx.x * 256 + threadIdx.x;
    if (i < N_EDGES) atomicAdd(&cnt[dst[i]], 1);
}

__global__ __launch_bounds__(SCAN_B) void scan_block(const int* __restrict__ cnt,
                                                     int* __restrict__ offs,
                                                     int* __restrict__ bsum) {
    const int t = threadIdx.x, b = blockIdx.x;
    const int i = b * SCAN_B + t;
    int v = (i < N_NODES) ? cnt[i] : 0;
    __shared__ int s[SCAN_B];
    s[t] = v;
    __syncthreads();
    for (int o = 1; o < SCAN_B; o <<= 1) {
        int add = (t >= o) ? s[t - o] : 0;
        __syncthreads();
        s[t] += add;
        __syncthreads();
    }
    if (i < N_NODES) offs[i] = s[t];          // inclusive within block (temporary)
    if (t == SCAN_B - 1) bsum[b] = s[t];
}

__global__ __launch_bounds__(128) void scan_tops(int* __restrict__ bsum) {
    const int t = threadIdx.x;
    __shared__ int s[128];
    int v = (t < SCAN_NBLK) ? bsum[t] : 0;
    s[t] = v;
    __syncthreads();
    for (int o = 1; o < 128; o <<= 1) {
        int add = (t >= o) ? s[t - o] : 0;
        __syncthreads();
        s[t] += add;
        __syncthreads();
    }
    if (t < SCAN_NBLK) bsum[t] = s[t] - v;    // exclusive
}

__global__ __launch_bounds__(SCAN_B) void finalize_off(const int* __restrict__ cnt,
                                                       int* __restrict__ offs,
                                                       const int* __restrict__ bsum,
                                                       int* __restrict__ cur) {
    const int i = blockIdx.x * SCAN_B + threadIdx.x;
    if (i < N_NODES) {
        int e = offs[i] - cnt[i] + bsum[blockIdx.x];   // global exclusive prefix
        offs[i] = e;
        cur[i]  = e;
    }
    if (i == 0) offs[N_NODES] = N_EDGES;
}

// build dst-sorted edge list: eord[pos]=edge id, ssrc[pos]=src, sdst[pos]=dst
// (sdst is nondecreasing along pos by construction of the counting sort)
__global__ __launch_bounds__(256) void scatter_build(const int* __restrict__ dst,
                                                     const int* __restrict__ src,
                                                     int* __restrict__ cur,
                                                     int* __restrict__ eord,
                                                     int* __restrict__ ssrc,
                                                     int* __restrict__ sdst) {
    int i = blockIdx.x * 256 + threadIdx.x;
    if (i < N_EDGES) {
        int d   = dst[i];
        int pos = atomicAdd(&cur[d], 1);
        eord[pos] = i;
        ssrc[pos] = src[i];
        sdst[pos] = d;
    }
}

// ---------------- edge-centric kernel over dst-sorted positions ----------------
// Dense 64-edge tiles (no padding, no offs chase): eord/ssrc/sdst stream,
// eb is one-level indirect with 16 independent rows in flight per wave.
// Epilogue exploits monotone sdst: full-wave single-node fast path (1 atomic
// set), else per-quad run-merging -> ~11M atomics vs round-0's 51.2M.
__global__ __launch_bounds__(256) void sorted_edge_kernel(
    const float* __restrict__ x,        // [N, 64]
    const float* __restrict__ eb,       // [E, 128]
    const int*   __restrict__ eord,     // [E]
    const int*   __restrict__ ssrc,     // [E]
    const int*   __restrict__ sdst,     // [E] nondecreasing
    const float* __restrict__ W,        // [64, 128]
    const float* __restrict__ bias_p,   // [64]
    float*       __restrict__ out)      // [N, 64] (pre-zeroed)
{
    const int lane = threadIdx.x & 63;
    const int wv   = threadIdx.x >> 6;
    const int l15  = lane & 15;
    const int quad = lane >> 4;

    // B-operand fragments of W' (W'[r][d] = W[d][r]); loaded once per block
    bf16x8 wfrag[4][4];
    #pragma unroll
    for (int nt = 0; nt < 4; ++nt) {
        const int d = nt * 16 + l15;
        #pragma unroll
        for (int kt = 0; kt < 4; ++kt) {
            const float* p = W + d * D_RADIAL + kt * 32 + quad * 8;
            s16x8 s;
            #pragma unroll
            for (int j = 0; j < 8; ++j) s[j] = (short)f2bf_rne(p[j]);
            wfrag[nt][kt] = __builtin_bit_cast(bf16x8, s);
        }
    }
    float bv[4];
    #pragma unroll
    for (int nt = 0; nt < 4; ++nt) bv[nt] = bias_p[nt * 16 + l15];

    for (int tile = blockIdx.x; tile < NTILES; tile += gridDim.x) {
        const int ebase = tile * 64 + wv * 16;   // this wave's 16 sorted positions
        const int erow  = ebase + quad * 4;

        // --- streaming index loads (all independent, issued together) ---
        const int ea  = eord[ebase + l15];                    // A-row edge id
        const int4 s4 = *(const int4*)(ssrc + erow);          // 4 src nodes (quad rows)
        const int4 n4 = *(const int4*)(sdst + erow);          // 4 dst nodes (monotone)
        const int sr[4]  = {s4.x, s4.y, s4.z, s4.w};
        const int ndv[4] = {n4.x, n4.y, n4.z, n4.w};

        // --- x gather (random 256B rows, L2/L3-resident: x is 12.8 MB) ---
        float xv[4][4];
        #pragma unroll
        for (int reg = 0; reg < 4; ++reg) {
            const float* xrow = x + (long)sr[reg] * D_IN;
            #pragma unroll
            for (int nt = 0; nt < 4; ++nt)
                xv[reg][nt] = xrow[nt * 16 + l15];
        }

        // --- eb loads (16 independent 512B rows per wave) + MFMA ---
        f32x4 acc[4];
        #pragma unroll
        for (int nt = 0; nt < 4; ++nt) acc[nt] = (f32x4){0.f, 0.f, 0.f, 0.f};

        const float* pbase = eb + (long)ea * D_RADIAL + quad * 8;
        #pragma unroll
        for (int kt = 0; kt < 4; ++kt) {
            f32x4 a0 = *(const f32x4*)(pbase + kt * 32);
            f32x4 a1 = *(const f32x4*)(pbase + kt * 32 + 4);
            int4 packed;
            packed.x = pack_bf16_pair(a0[0], a0[1]);
            packed.y = pack_bf16_pair(a0[2], a0[3]);
            packed.z = pack_bf16_pair(a1[0], a1[1]);
            packed.w = pack_bf16_pair(a1[2], a1[3]);
            bf16x8 afrag = __builtin_bit_cast(bf16x8, packed);
            #pragma unroll
            for (int nt = 0; nt < 4; ++nt)
                acc[nt] = __builtin_amdgcn_mfma_f32_16x16x32_bf16(
                    afrag, wfrag[nt][kt], acc[nt], 0, 0, 0);
        }

        // --- epilogue: D[row=quad*4+reg][col=l15]; rows are sorted positions ---
        // monotone node ids: uniform-wave iff row0.node == row15.node
        const int n_first = __shfl(ndv[0], 0, 64);   // row 0's node
        const int n_last  = __shfl(ndv[3], 48, 64);  // row 15's node
        if (n_first == n_last) {
            // whole 16-row tile belongs to one node: reduce, single atomic set
            #pragma unroll
            for (int nt = 0; nt < 4; ++nt) {
                float s = (acc[nt][0] + bv[nt]) * xv[0][nt]
                        + (acc[nt][1] + bv[nt]) * xv[1][nt]
                        + (acc[nt][2] + bv[nt]) * xv[2][nt]
                        + (acc[nt][3] + bv[nt]) * xv[3][nt];
                s += __shfl_xor(s, 16, 64);
                s += __shfl_xor(s, 32, 64);
                if (quad == 0)
                    unsafeAtomicAdd(out + (long)n_first * D_IN + nt * 16 + l15, s);
            }
        } else {
            // per-quad run merge (ndv monotone; comparisons uniform within quad)
            #pragma unroll
            for (int nt = 0; nt < 4; ++nt) {
                float a = (acc[nt][0] + bv[nt]) * xv[0][nt];
                #pragma unroll
                for (int reg = 1; reg < 4; ++reg) {
                    const float v = (acc[nt][reg] + bv[nt]) * xv[reg][nt];
                    if (ndv[reg] == ndv[reg - 1]) {
                        a += v;
                    } else {
                        unsafeAtomicAdd(out + (long)ndv[reg - 1] * D_IN + nt * 16 + l15, a);
                        a = v;
                    }
                }
                unsafeAtomicAdd(out + (long)ndv[3] * D_IN + nt * 16 + l15, a);
            }
        }
    }
}

// ---------------- legacy fallback (atomic) kernel — unchanged ----------------
__global__ __launch_bounds__(256) void edge_msg_kernel(
    const float* __restrict__ x,
    const float* __restrict__ eb,
    const int*   __restrict__ src,
    const int*   __restrict__ dst,
    const float* __restrict__ W,
    const float* __restrict__ bias_p,
    float*       __restrict__ out)
{
    const int lane = threadIdx.x & 63;
    const int wv   = threadIdx.x >> 6;
    const int l15  = lane & 15;
    const int quad = lane >> 4;

    bf16x8 wfrag[4][4];
    #pragma unroll
    for (int nt = 0; nt < 4; ++nt) {
        const int d = nt * 16 + l15;
        #pragma unroll
        for (int kt = 0; kt < 4; ++kt) {
            const float* p = W + d * D_RADIAL + kt * 32 + quad * 8;
            s16x8 s;
            #pragma unroll
            for (int j = 0; j < 8; ++j) s[j] = (short)f2bf_rne(p[j]);
            wfrag[nt][kt] = __builtin_bit_cast(bf16x8, s);
        }
    }
    float bv[4];
    #pragma unroll
    for (int nt = 0; nt < 4; ++nt) bv[nt] = bias_p[nt * 16 + l15];

    for (int tile = blockIdx.x; tile < NTILES; tile += gridDim.x) {
        const int ebase = tile * 64 + wv * 16;

        f32x4 acc[4];
        #pragma unroll
        for (int nt = 0; nt < 4; ++nt) acc[nt] = (f32x4){0.f, 0.f, 0.f, 0.f};

        #pragma unroll
        for (int kt = 0; kt < 4; ++kt) {
            const float* p = eb + (long)(ebase + l15) * D_RADIAL + kt * 32 + quad * 8;
            f32x4 a0 = *(const f32x4*)(p);
            f32x4 a1 = *(const f32x4*)(p + 4);
            int4 packed;
            packed.x = pack_bf16_pair(a0[0], a0[1]);
            packed.y = pack_bf16_pair(a0[2], a0[3]);
            packed.z = pack_bf16_pair(a1[0], a1[1]);
            packed.w = pack_bf16_pair(a1[2], a1[3]);
            bf16x8 afrag = __builtin_bit_cast(bf16x8, packed);
            #pragma unroll
            for (int nt = 0; nt < 4; ++nt)
                acc[nt] = __builtin_amdgcn_mfma_f32_16x16x32_bf16(
                    afrag, wfrag[nt][kt], acc[nt], 0, 0, 0);
        }

        const int erow = ebase + quad * 4;
        #pragma unroll
        for (int reg = 0; reg < 4; ++reg) {
            const int e  = erow + reg;
            const int sv = src[e];
            const int dv = dst[e];
            const float* xrow = x   + (long)sv * D_IN;
            float*       orow = out + (long)dv * D_IN;
            #pragma unroll
            for (int nt = 0; nt < 4; ++nt) {
                const int d = nt * 16 + l15;
                const float val = (acc[nt][reg] + bv[nt]) * xrow[d];
                unsafeAtomicAdd(orow + d, val);
            }
        }
    }
}

extern "C" void kernel_launch(void* const* d_in, const int* in_sizes, int n_in,
                              void* d_out, int out_size, void* d_ws, size_t ws_size,
                              hipStream_t stream) {
    const float* x    = (const float*)d_in[0];
    const float* eb   = (const float*)d_in[1];
    const int*   src  = (const int*)d_in[2];
    const int*   dst  = (const int*)d_in[3];
    const float* W    = (const float*)d_in[4];
    const float* bias = (const float*)d_in[5];
    float* out = (float*)d_out;

    if (ws_size >= WS_REQUIRED) {
        // counting-sort by dst, then edge-centric MFMA kernel over sorted
        // positions with run-merged atomics.
        char* ws   = (char*)d_ws;
        int*  cnt  = (int*)(ws + WS_CNT);
        int*  offs = (int*)(ws + WS_OFF);
        int*  cur  = (int*)(ws + WS_CUR);
        int*  bsum = (int*)(ws + WS_BSUM);
        int*  eord = (int*)(ws + WS_EORD);
        int*  ssrc = (int*)(ws + WS_SSRC);
        int*  sdst = (int*)(ws + WS_SDST);

        hipMemsetAsync(cnt, 0, (size_t)N_NODES * 4, stream);
        hipMemsetAsync(d_out, 0, (size_t)N_NODES * D_IN * sizeof(float), stream);
        hist_kernel   <<<(N_EDGES + 255) / 256, 256, 0, stream>>>(dst, cnt);
        scan_block    <<<SCAN_NBLK, SCAN_B, 0, stream>>>(cnt, offs, bsum);
        scan_tops     <<<1, 128, 0, stream>>>(bsum);
        finalize_off  <<<SCAN_NBLK, SCAN_B, 0, stream>>>(cnt, offs, bsum, cur);
        scatter_build <<<(N_EDGES + 255) / 256, 256, 0, stream>>>(dst, src, cur,
                                                                  eord, ssrc, sdst);
        sorted_edge_kernel<<<1280, 256, 0, stream>>>(x, eb, eord, ssrc, sdst,
                                                     W, bias, out);
    } else {
        // fallback: original atomic kernel (harness poisons d_out -> zero it first)
        hipMemsetAsync(d_out, 0, (size_t)N_NODES * D_IN * sizeof(float), stream);
        edge_msg_kernel<<<1024, 256, 0, stream>>>(x, eb, src, dst, W, bias, out);
    }
}

// Round 14
// 684.346 us; speedup vs baseline: 1.0490x; 1.0490x over previous
//
#include <hip/hip_runtime.h>

#define N_NODES  50000
#define N_EDGES  800000
#define D_IN     64
#define D_RADIAL 128
#define NTILES   (N_EDGES / 64)   // 12500, exact (fallback kernel)

typedef __bf16 bf16x8 __attribute__((ext_vector_type(8)));
typedef float  f32x4  __attribute__((ext_vector_type(4)));
typedef short  s16x8  __attribute__((ext_vector_type(8)));

// pack two f32 -> two bf16 (truncation) in one v_perm (MFMA inputs)
__device__ inline unsigned int pack_bf16_pair(float lo, float hi) {
    return __builtin_amdgcn_perm(__float_as_uint(hi), __float_as_uint(lo), 0x07060302u);
}

// round-to-nearest-even f32 -> bf16
__device__ inline unsigned short f2bf_rne(float f) {
    unsigned int u = __float_as_uint(f);
    u += 0x7FFFu + ((u >> 16) & 1u);
    return (unsigned short)(u >> 16);
}

__device__ inline int mini(int a, int b) { return a < b ? a : b; }
__device__ inline int clamp0(int a)      { return a < 0 ? 0 : a; }

// ---------------- workspace layout (CSR path) ----------------
constexpr size_t ws_align(size_t x) { return (x + 255) & ~(size_t)255; }
constexpr size_t WS_CNT  = 0;                                             // int[N_NODES]
constexpr size_t WS_OFF  = ws_align(WS_CNT  + (size_t)N_NODES * 4);       // int[N_NODES+1]
constexpr size_t WS_CUR  = ws_align(WS_OFF  + (size_t)(N_NODES + 1) * 4); // int[N_NODES]
constexpr size_t WS_BSUM = ws_align(WS_CUR  + (size_t)N_NODES * 4);       // int[128]
constexpr size_t WS_EORD = ws_align(WS_BSUM + 512);                       // int[N_EDGES]
constexpr size_t WS_SSRC = ws_align(WS_EORD + (size_t)N_EDGES * 4);       // int[N_EDGES]
constexpr size_t WS_REQUIRED = WS_SSRC + (size_t)N_EDGES * 4;             // ~13 MB

#define SCAN_B    512
#define SCAN_NBLK ((N_NODES + SCAN_B - 1) / SCAN_B)   // 98
static_assert(SCAN_NBLK <= 128, "scan_tops assumes <=128 blocks");

// ---------------- sort kernels ----------------
__global__ __launch_bounds__(256) void hist_kernel(const int* __restrict__ dst,
                                                   int* __restrict__ cnt) {
    int i = blockIdx.x * 256 + threadIdx.x;
    if (i < N_EDGES) atomicAdd(&cnt[dst[i]], 1);
}

__global__ __launch_bounds__(SCAN_B) void scan_block(const int* __restrict__ cnt,
                                                     int* __restrict__ offs,
                                                     int* __restrict__ bsum) {
    const int t = threadIdx.x, b = blockIdx.x;
    const int i = b * SCAN_B + t;
    int v = (i < N_NODES) ? cnt[i] : 0;
    __shared__ int s[SCAN_B];
    s[t] = v;
    __syncthreads();
    for (int o = 1; o < SCAN_B; o <<= 1) {
        int add = (t >= o) ? s[t - o] : 0;
        __syncthreads();
        s[t] += add;
        __syncthreads();
    }
    if (i < N_NODES) offs[i] = s[t];          // inclusive within block (temporary)
    if (t == SCAN_B - 1) bsum[b] = s[t];
}

__global__ __launch_bounds__(128) void scan_tops(int* __restrict__ bsum) {
    const int t = threadIdx.x;
    __shared__ int s[128];
    int v = (t < SCAN_NBLK) ? bsum[t] : 0;
    s[t] = v;
    __syncthreads();
    for (int o = 1; o < 128; o <<= 1) {
        int add = (t >= o) ? s[t - o] : 0;
        __syncthreads();
        s[t] += add;
        __syncthreads();
    }
    if (t < SCAN_NBLK) bsum[t] = s[t] - v;    // exclusive
}

__global__ __launch_bounds__(SCAN_B) void finalize_off(const int* __restrict__ cnt,
                                                       int* __restrict__ offs,
                                                       const int* __restrict__ bsum,
                                                       int* __restrict__ cur) {
    const int i = blockIdx.x * SCAN_B + threadIdx.x;
    if (i < N_NODES) {
        int e = offs[i] - cnt[i] + bsum[blockIdx.x];   // global exclusive prefix
        offs[i] = e;
        cur[i]  = e;
    }
    if (i == 0) offs[N_NODES] = N_EDGES;
}

// build dst-sorted edge list: eord[pos] = edge id, ssrc[pos] = src of that edge
__global__ __launch_bounds__(256) void scatter_build(const int* __restrict__ dst,
                                                     const int* __restrict__ src,
                                                     int* __restrict__ cur,
                                                     int* __restrict__ eord,
                                                     int* __restrict__ ssrc) {
    int i = blockIdx.x * 256 + threadIdx.x;
    if (i < N_EDGES) {
        int pos = atomicAdd(&cur[dst[i]], 1);
        eord[pos] = i;
        ssrc[pos] = src[i];
    }
}

// ---------------- fused 2-node-interleaved kernel: one wave owns TWO adjacent nodes ----------------
// Doubles per-wave MLP vs node_kernel: 32 independent eb rows in flight per
// iteration (16 per node). All loads unconditional with clamped indices; an
// exhausted node's loads degrade to L2-hit dummies, masked in the epilogue —
// the same mechanism that bought round 11's +87 us, extended across the pair.
// Adjacent pairing => sorted ranges contiguous (j0B == j1A): one offs triple.
__global__ __launch_bounds__(256) void node2_kernel(
    const float* __restrict__ x,        // [N, 64]
    const float* __restrict__ eb,       // [E, 128]
    const int*   __restrict__ eord,     // [E] dst-sorted -> edge id
    const int*   __restrict__ ssrc,     // [E] dst-sorted -> src node
    const int*   __restrict__ offs,     // [N+1]
    const float* __restrict__ W,        // [64, 128]
    const float* __restrict__ bias_p,   // [64]
    float*       __restrict__ out)      // [N, 64]
{
    const int lane = threadIdx.x & 63;
    const int wv   = threadIdx.x >> 6;
    const int l15  = lane & 15;
    const int quad = lane >> 4;

    // B-operand fragments of W' (W'[r][d] = W[d][r]); loaded once per block
    bf16x8 wfrag[4][4];
    #pragma unroll
    for (int nt = 0; nt < 4; ++nt) {
        const int d = nt * 16 + l15;
        #pragma unroll
        for (int kt = 0; kt < 4; ++kt) {
            const float* p = W + d * D_RADIAL + kt * 32 + quad * 8;
            s16x8 s;
            #pragma unroll
            for (int j = 0; j < 8; ++j) s[j] = (short)f2bf_rne(p[j]);
            wfrag[nt][kt] = __builtin_bit_cast(bf16x8, s);
        }
    }
    float bv[4];
    #pragma unroll
    for (int nt = 0; nt < 4; ++nt) bv[nt] = bias_p[nt * 16 + l15];

    const int wid = blockIdx.x * 4 + wv;
    const int nw  = gridDim.x * 4;
    for (int nA = wid * 2; nA < N_NODES; nA += nw * 2) {
        const int  nB   = nA + 1;
        const bool hasB = (nB < N_NODES);
        const int  j0A  = offs[nA];
        const int  j1A  = offs[nA + 1];
        const int  j1B  = hasB ? offs[nB + 1] : j1A;
        // adjacent nodes: B's run starts where A's ends
        const int  j0B  = j1A;

        float naccA[4] = {0.f, 0.f, 0.f, 0.f};
        float naccB[4] = {0.f, 0.f, 0.f, 0.f};

        int pA = j0A, pB = j0B;
        while (pA < j1A || pB < j1B) {
            // --- clamped index loads for BOTH nodes (branch-free, batch-issued) ---
            const int eA = eord[clamp0(mini(pA + l15, j1A - 1))];
            const int eB = eord[clamp0(mini(pB + l15, j1B - 1))];
            int srA[4], srB[4];
            #pragma unroll
            for (int r = 0; r < 4; ++r) {
                srA[r] = ssrc[clamp0(mini(pA + quad * 4 + r, j1A - 1))];
                srB[r] = ssrc[clamp0(mini(pB + quad * 4 + r, j1B - 1))];
            }

            // --- eb loads (2 x 16 independent 512B rows in flight) + MFMA ---
            f32x4 accA[4], accB[4];
            #pragma unroll
            for (int nt = 0; nt < 4; ++nt) {
                accA[nt] = (f32x4){0.f, 0.f, 0.f, 0.f};
                accB[nt] = (f32x4){0.f, 0.f, 0.f, 0.f};
            }
            const float* pbA = eb + (long)eA * D_RADIAL + quad * 8;
            const float* pbB = eb + (long)eB * D_RADIAL + quad * 8;
            #pragma unroll
            for (int kt = 0; kt < 4; ++kt) {
                f32x4 a0A = *(const f32x4*)(pbA + kt * 32);
                f32x4 a1A = *(const f32x4*)(pbA + kt * 32 + 4);
                f32x4 a0B = *(const f32x4*)(pbB + kt * 32);
                f32x4 a1B = *(const f32x4*)(pbB + kt * 32 + 4);
                int4 pkA, pkB;
                pkA.x = pack_bf16_pair(a0A[0], a0A[1]);
                pkA.y = pack_bf16_pair(a0A[2], a0A[3]);
                pkA.z = pack_bf16_pair(a1A[0], a1A[1]);
                pkA.w = pack_bf16_pair(a1A[2], a1A[3]);
                pkB.x = pack_bf16_pair(a0B[0], a0B[1]);
                pkB.y = pack_bf16_pair(a0B[2], a0B[3]);
                pkB.z = pack_bf16_pair(a1B[0], a1B[1]);
                pkB.w = pack_bf16_pair(a1B[2], a1B[3]);
                bf16x8 afA = __builtin_bit_cast(bf16x8, pkA);
                bf16x8 afB = __builtin_bit_cast(bf16x8, pkB);
                #pragma unroll
                for (int nt = 0; nt < 4; ++nt)
                    accA[nt] = __builtin_amdgcn_mfma_f32_16x16x32_bf16(
                        afA, wfrag[nt][kt], accA[nt], 0, 0, 0);
                #pragma unroll
                for (int nt = 0; nt < 4; ++nt)
                    accB[nt] = __builtin_amdgcn_mfma_f32_16x16x32_bf16(
                        afB, wfrag[nt][kt], accB[nt], 0, 0, 0);
            }

            // --- x gathers (L2/L3-resident; issued late, consumed in epilogue) ---
            float xvA[4][4], xvB[4][4];
            #pragma unroll
            for (int r = 0; r < 4; ++r) {
                const float* xrA = x + (long)srA[r] * D_IN;
                const float* xrB = x + (long)srB[r] * D_IN;
                #pragma unroll
                for (int nt = 0; nt < 4; ++nt) {
                    xvA[r][nt] = xrA[nt * 16 + l15];
                    xvB[r][nt] = xrB[nt * 16 + l15];
                }
            }

            // --- epilogue: D[row=quad*4+reg][col=l15]; invalid rows mask to 0 ---
            #pragma unroll
            for (int reg = 0; reg < 4; ++reg) {
                const bool rvA = (pA + quad * 4 + reg) < j1A;
                const bool rvB = (pB + quad * 4 + reg) < j1B;
                #pragma unroll
                for (int nt = 0; nt < 4; ++nt) {
                    const float vA = (accA[nt][reg] + bv[nt]) * xvA[reg][nt];
                    const float vB = (accB[nt][reg] + bv[nt]) * xvB[reg][nt];
                    naccA[nt] += rvA ? vA : 0.f;
                    naccB[nt] += rvB ? vB : 0.f;
                }
            }
            pA += 16;
            pB += 16;
        }

        // uniform cross-quad reduction + single plain store per node
        #pragma unroll
        for (int nt = 0; nt < 4; ++nt) {
            naccA[nt] += __shfl_xor(naccA[nt], 16, 64);
            naccA[nt] += __shfl_xor(naccA[nt], 32, 64);
            naccB[nt] += __shfl_xor(naccB[nt], 16, 64);
            naccB[nt] += __shfl_xor(naccB[nt], 32, 64);
        }
        if (quad == 0) {
            float* orA = out + (size_t)nA * D_IN;
            #pragma unroll
            for (int nt = 0; nt < 4; ++nt)
                orA[nt * 16 + l15] = naccA[nt];
            if (hasB) {
                float* orB = out + (size_t)nB * D_IN;
                #pragma unroll
                for (int nt = 0; nt < 4; ++nt)
                    orB[nt * 16 + l15] = naccB[nt];
            }
        }
    }
}

// ---------------- legacy fallback (atomic) kernel — unchanged ----------------
__global__ __launch_bounds__(256) void edge_msg_kernel(
    const float* __restrict__ x,
    const float* __restrict__ eb,
    const int*   __restrict__ src,
    const int*   __restrict__ dst,
    const float* __restrict__ W,
    const float* __restrict__ bias_p,
    float*       __restrict__ out)
{
    const int lane = threadIdx.x & 63;
    const int wv   = threadIdx.x >> 6;
    const int l15  = lane & 15;
    const int quad = lane >> 4;

    bf16x8 wfrag[4][4];
    #pragma unroll
    for (int nt = 0; nt < 4; ++nt) {
        const int d = nt * 16 + l15;
        #pragma unroll
        for (int kt = 0; kt < 4; ++kt) {
            const float* p = W + d * D_RADIAL + kt * 32 + quad * 8;
            s16x8 s;
            #pragma unroll
            for (int j = 0; j < 8; ++j) s[j] = (short)f2bf_rne(p[j]);
            wfrag[nt][kt] = __builtin_bit_cast(bf16x8, s);
        }
    }
    float bv[4];
    #pragma unroll
    for (int nt = 0; nt < 4; ++nt) bv[nt] = bias_p[nt * 16 + l15];

    for (int tile = blockIdx.x; tile < NTILES; tile += gridDim.x) {
        const int ebase = tile * 64 + wv * 16;

        f32x4 acc[4];
        #pragma unroll
        for (int nt = 0; nt < 4; ++nt) acc[nt] = (f32x4){0.f, 0.f, 0.f, 0.f};

        #pragma unroll
        for (int kt = 0; kt < 4; ++kt) {
            const float* p = eb + (long)(ebase + l15) * D_RADIAL + kt * 32 + quad * 8;
            f32x4 a0 = *(const f32x4*)(p);
            f32x4 a1 = *(const f32x4*)(p + 4);
            int4 packed;
            packed.x = pack_bf16_pair(a0[0], a0[1]);
            packed.y = pack_bf16_pair(a0[2], a0[3]);
            packed.z = pack_bf16_pair(a1[0], a1[1]);
            packed.w = pack_bf16_pair(a1[2], a1[3]);
            bf16x8 afrag = __builtin_bit_cast(bf16x8, packed);
            #pragma unroll
            for (int nt = 0; nt < 4; ++nt)
                acc[nt] = __builtin_amdgcn_mfma_f32_16x16x32_bf16(
                    afrag, wfrag[nt][kt], acc[nt], 0, 0, 0);
        }

        const int erow = ebase + quad * 4;
        #pragma unroll
        for (int reg = 0; reg < 4; ++reg) {
            const int e  = erow + reg;
            const int sv = src[e];
            const int dv = dst[e];
            const float* xrow = x   + (long)sv * D_IN;
            float*       orow = out + (long)dv * D_IN;
            #pragma unroll
            for (int nt = 0; nt < 4; ++nt) {
                const int d = nt * 16 + l15;
                const float val = (acc[nt][reg] + bv[nt]) * xrow[d];
                unsafeAtomicAdd(orow + d, val);
            }
        }
    }
}

extern "C" void kernel_launch(void* const* d_in, const int* in_sizes, int n_in,
                              void* d_out, int out_size, void* d_ws, size_t ws_size,
                              hipStream_t stream) {
    const float* x    = (const float*)d_in[0];
    const float* eb   = (const float*)d_in[1];
    const int*   src  = (const int*)d_in[2];
    const int*   dst  = (const int*)d_in[3];
    const float* W    = (const float*)d_in[4];
    const float* bias = (const float*)d_in[5];
    float* out = (float*)d_out;

    if (ws_size >= WS_REQUIRED) {
        // CSR fused path: sort edges by dst, then 2-node-interleaved MFMA kernel.
        // No float atomics, no intermediate message buffer.
        char* ws   = (char*)d_ws;
        int*  cnt  = (int*)(ws + WS_CNT);
        int*  offs = (int*)(ws + WS_OFF);
        int*  cur  = (int*)(ws + WS_CUR);
        int*  bsum = (int*)(ws + WS_BSUM);
        int*  eord = (int*)(ws + WS_EORD);
        int*  ssrc = (int*)(ws + WS_SSRC);

        hipMemsetAsync(cnt, 0, (size_t)N_NODES * 4, stream);
        hist_kernel   <<<(N_EDGES + 255) / 256, 256, 0, stream>>>(dst, cnt);
        scan_block    <<<SCAN_NBLK, SCAN_B, 0, stream>>>(cnt, offs, bsum);
        scan_tops     <<<1, 128, 0, stream>>>(bsum);
        finalize_off  <<<SCAN_NBLK, SCAN_B, 0, stream>>>(cnt, offs, bsum, cur);
        scatter_build <<<(N_EDGES + 255) / 256, 256, 0, stream>>>(dst, src, cur, eord, ssrc);
        // node2_kernel writes every output element -> no d_out memset needed
        node2_kernel  <<<2560, 256, 0, stream>>>(x, eb, eord, ssrc, offs, W, bias, out);
    } else {
        // fallback: original atomic kernel (harness poisons d_out -> zero it first)
        hipMemsetAsync(d_out, 0, (size_t)N_NODES * D_IN * sizeof(float), stream);
        edge_msg_kernel<<<1024, 256, 0, stream>>>(x, eb, src, dst, W, bias, out);
    }
}